// Round 1
// baseline (465.610 us; speedup 1.0000x reference)
//
#include <hip/hip_runtime.h>
#include <math.h>

#define NROWS 16384
#define DM    2048
#define RK    16
#define LRc    1e-3f
#define L2c    1e-4f
#define MOMc   0.9f
#define SCALEc 0.1f
#define LNEPS  1e-5f

// ---------------------------------------------------------------------------
// K_main: fused per-row pass over k,v.
//   kC[n,:]   = k[n,:] @ C                       (rank-16)
//   ro[n,:]   = SCALE * kC[n,:] @ B^T + k[n,:]*D (linearized tanh; error ~1e-6)
//   err[n,:]  = v[n,:] - ro[n,:]
//   errB[n,:] = err[n,:] @ B
//   colsum[d] += k[n,d]
// grid 256 blocks x 512 threads; block = 64 rows; thread owns 4 columns.
// B,C tiles live in registers (64+64 VGPRs). Per-row [16]-reductions via a
// 2-stage LDS tree, software-pipelined: row n's kC partials reduce together
// with row n-1's errB partials (3 barriers/row).
// ---------------------------------------------------------------------------
__global__ __launch_bounds__(512, 2) void k_main(
    const float* __restrict__ k, const float* __restrict__ v,
    const float* __restrict__ B, const float* __restrict__ C,
    const float* __restrict__ Dd,
    float* __restrict__ ro, float* __restrict__ kC,
    float* __restrict__ errB, float* __restrict__ colsum)
{
    __shared__ float p_lds[512][36];   // 36-pad: 16B-aligned rows, conflict-free stage1
    __shared__ float s_lds[16][36];
    __shared__ float kCsh[16];

    const int t  = threadIdx.x;
    const int d0 = t * 4;
    const int row0 = blockIdx.x * 64;

    float Breg[4][16], Creg[4][16], Dreg[4];
    #pragma unroll
    for (int i = 0; i < 4; ++i) {
        #pragma unroll
        for (int q = 0; q < 4; ++q) {
            float4 b4 = *(const float4*)(B + (size_t)(d0 + i) * RK + q * 4);
            float4 c4 = *(const float4*)(C + (size_t)(d0 + i) * RK + q * 4);
            Breg[i][q*4+0] = b4.x; Breg[i][q*4+1] = b4.y;
            Breg[i][q*4+2] = b4.z; Breg[i][q*4+3] = b4.w;
            Creg[i][q*4+0] = c4.x; Creg[i][q*4+1] = c4.y;
            Creg[i][q*4+2] = c4.z; Creg[i][q*4+3] = c4.w;
        }
        Dreg[i] = Dd[d0 + i];
    }

    float cs[4]   = {0.f, 0.f, 0.f, 0.f};
    float errp[4] = {0.f, 0.f, 0.f, 0.f};   // err of previous row

    float4 k4 = *(const float4*)(k + (size_t)row0 * DM + d0);
    float4 v4 = *(const float4*)(v + (size_t)row0 * DM + d0);

    for (int rr = 0; rr < 64; ++rr) {
        const int n = row0 + rr;
        const float ka[4] = {k4.x, k4.y, k4.z, k4.w};
        const float va[4] = {v4.x, v4.y, v4.z, v4.w};

        // prefetch next row
        const int nn = (rr < 63) ? (n + 1) : n;
        float4 k4n = *(const float4*)(k + (size_t)nn * DM + d0);
        float4 v4n = *(const float4*)(v + (size_t)nn * DM + d0);

        // partials: kC of row n, errB of row n-1
        float pk[16], pe[16];
        #pragma unroll
        for (int r = 0; r < 16; ++r) {
            pk[r] = ka[0]*Creg[0][r] + ka[1]*Creg[1][r]
                  + ka[2]*Creg[2][r] + ka[3]*Creg[3][r];
            pe[r] = errp[0]*Breg[0][r] + errp[1]*Breg[1][r]
                  + errp[2]*Breg[2][r] + errp[3]*Breg[3][r];
        }
        {
            float4* prow = (float4*)&p_lds[t][0];
            prow[0] = make_float4(pk[0],  pk[1],  pk[2],  pk[3]);
            prow[1] = make_float4(pk[4],  pk[5],  pk[6],  pk[7]);
            prow[2] = make_float4(pk[8],  pk[9],  pk[10], pk[11]);
            prow[3] = make_float4(pk[12], pk[13], pk[14], pk[15]);
            prow[4] = make_float4(pe[0],  pe[1],  pe[2],  pe[3]);
            prow[5] = make_float4(pe[4],  pe[5],  pe[6],  pe[7]);
            prow[6] = make_float4(pe[8],  pe[9],  pe[10], pe[11]);
            prow[7] = make_float4(pe[12], pe[13], pe[14], pe[15]);
        }
        __syncthreads();
        {   // stage1: 512 threads -> 16 groups x 32 cols
            const int col = t & 31, grp = t >> 5;
            float s = 0.f;
            #pragma unroll
            for (int i = 0; i < 32; ++i) s += p_lds[grp * 32 + i][col];
            s_lds[grp][col] = s;
        }
        __syncthreads();
        if (t < 32) {   // stage2
            float s = 0.f;
            #pragma unroll
            for (int g = 0; g < 16; ++g) s += s_lds[g][t];
            if (t < 16) {
                kCsh[t] = s;
                kC[(size_t)n * RK + t] = s;
            } else if (rr > 0) {
                errB[(size_t)(n - 1) * RK + (t - 16)] = s;
            }
        }
        __syncthreads();

        float kc[16];
        #pragma unroll
        for (int q = 0; q < 4; ++q) {
            float4 c4 = *(const float4*)&kCsh[q * 4];
            kc[q*4+0] = c4.x; kc[q*4+1] = c4.y; kc[q*4+2] = c4.z; kc[q*4+3] = c4.w;
        }
        float roa[4];
        #pragma unroll
        for (int i = 0; i < 4; ++i) {
            float s = 0.f;
            #pragma unroll
            for (int r = 0; r < 16; ++r) s += kc[r] * Breg[i][r];
            roa[i] = SCALEc * s + ka[i] * Dreg[i];
            errp[i] = va[i] - roa[i];
            cs[i] += ka[i];
        }
        *(float4*)(ro + (size_t)n * DM + d0) = make_float4(roa[0], roa[1], roa[2], roa[3]);

        k4 = k4n; v4 = v4n;
    }

    // epilogue: errB of last row
    #pragma unroll
    for (int r = 0; r < 16; ++r) {
        p_lds[t][16 + r] = errp[0]*Breg[0][r] + errp[1]*Breg[1][r]
                         + errp[2]*Breg[2][r] + errp[3]*Breg[3][r];
    }
    __syncthreads();
    {
        const int col = t & 31, grp = t >> 5;
        float s = 0.f;
        #pragma unroll
        for (int i = 0; i < 32; ++i) s += p_lds[grp * 32 + i][col];
        s_lds[grp][col] = s;
    }
    __syncthreads();
    if (t >= 16 && t < 32) {
        float s = 0.f;
        #pragma unroll
        for (int g = 0; g < 16; ++g) s += s_lds[g][t];
        errB[(size_t)(row0 + 63) * RK + (t - 16)] = s;
    }
    #pragma unroll
    for (int i = 0; i < 4; ++i) atomicAdd(colsum + d0 + i, cs[i]);
}

// ---------------------------------------------------------------------------
// K_grad: G1[d,r] = sum_n err[n,d]*kC[n,r],  G2[d,r] = sum_n k[n,d]*errB[n,r]
// err recomputed as v - ro. grid = 32 d-slabs x 16 n-chunks; block 256 = 4 waves,
// wave = 4-r group, lane = d within slab. Register accumulators + atomics.
// ---------------------------------------------------------------------------
__global__ __launch_bounds__(256) void k_grad(
    const float* __restrict__ k, const float* __restrict__ v,
    const float* __restrict__ ro, const float* __restrict__ kC,
    const float* __restrict__ errB,
    float* __restrict__ G1, float* __restrict__ G2)
{
    const int t = threadIdx.x;
    const int lane = t & 63;
    const int w = t >> 6;
    const int slab = blockIdx.x & 31;
    const int chunk = blockIdx.x >> 5;
    const int d = slab * 64 + lane;
    const int r0 = w * 4;

    float g1[4] = {0.f,0.f,0.f,0.f}, g2[4] = {0.f,0.f,0.f,0.f};
    const int nBeg = chunk * 1024, nEnd = nBeg + 1024;
    #pragma unroll 4
    for (int n = nBeg; n < nEnd; ++n) {
        const size_t base = (size_t)n * DM + d;
        const float kv = k[base];
        const float er = v[base] - ro[base];
        const float4 kc = *(const float4*)(kC + (size_t)n * RK + r0);
        const float4 eb = *(const float4*)(errB + (size_t)n * RK + r0);
        g1[0] += er * kc.x; g1[1] += er * kc.y; g1[2] += er * kc.z; g1[3] += er * kc.w;
        g2[0] += kv * eb.x; g2[1] += kv * eb.y; g2[2] += kv * eb.z; g2[3] += kv * eb.w;
    }
    #pragma unroll
    for (int j = 0; j < 4; ++j) {
        atomicAdd(G1 + (size_t)d * RK + r0 + j, g1[j]);
        atomicAdd(G2 + (size_t)d * RK + r0 + j, g2[j]);
    }
}

// ---------------------------------------------------------------------------
// K_ctc: CtC = C^T C, BtB = B^T B  (16x16 each). 16 blocks x 256 threads.
// ---------------------------------------------------------------------------
__global__ __launch_bounds__(256) void k_ctc(
    const float* __restrict__ B, const float* __restrict__ C,
    float* __restrict__ BtB, float* __restrict__ CtC)
{
    const int t = threadIdx.x;
    const int a = t >> 4, b = t & 15;
    const int dBeg = blockIdx.x * 128;
    float sc = 0.f, sb = 0.f;
    for (int d = dBeg; d < dBeg + 128; ++d) {
        sc += C[d * RK + a] * C[d * RK + b];
        sb += B[d * RK + a] * B[d * RK + b];
    }
    atomicAdd(CtC + a * RK + b, sc);
    atomicAdd(BtB + a * RK + b, sb);
}

// ---------------------------------------------------------------------------
// K_ln: k_mean = colsum/N; h1 = LayerNorm(k_mean)*gamma + beta. One block x256.
// ---------------------------------------------------------------------------
__global__ __launch_bounds__(256) void k_ln(
    const float* __restrict__ colsum,
    const float* __restrict__ gam, const float* __restrict__ bet,
    float* __restrict__ h1)
{
    __shared__ float red[256];
    __shared__ float mu_sh, var_sh;
    const int t = threadIdx.x;
    float x[8];
    float s = 0.f;
    #pragma unroll
    for (int i = 0; i < 8; ++i) {
        x[i] = colsum[t + 256 * i] * (1.0f / (float)NROWS);
        s += x[i];
    }
    red[t] = s; __syncthreads();
    for (int off = 128; off > 0; off >>= 1) {
        if (t < off) red[t] += red[t + off];
        __syncthreads();
    }
    if (t == 0) mu_sh = red[0] * (1.0f / (float)DM);
    __syncthreads();
    const float mu = mu_sh;
    float s2 = 0.f;
    #pragma unroll
    for (int i = 0; i < 8; ++i) { const float dd = x[i] - mu; s2 += dd * dd; }
    __syncthreads();
    red[t] = s2; __syncthreads();
    for (int off = 128; off > 0; off >>= 1) {
        if (t < off) red[t] += red[t + off];
        __syncthreads();
    }
    if (t == 0) var_sh = red[0] * (1.0f / (float)DM);
    __syncthreads();
    const float rstd = rsqrtf(var_sh + LNEPS);
    #pragma unroll
    for (int i = 0; i < 8; ++i) {
        const int d = t + 256 * i;
        h1[d] = (x[i] - mu) * rstd * gam[d] + bet[d];
    }
}

// ---------------------------------------------------------------------------
// K_gemv: h2[i] = silu(h1 . W1[i,:] + b1[i]). 512 blocks x 256 (wave/row).
// ---------------------------------------------------------------------------
__global__ __launch_bounds__(256) void k_gemv(
    const float* __restrict__ h1, const float* __restrict__ W1,
    const float* __restrict__ b1, float* __restrict__ h2)
{
    const int t = threadIdx.x;
    const int lane = t & 63;
    const int w = t >> 6;
    const int row = blockIdx.x * 4 + w;
    const float* wr = W1 + (size_t)row * DM;
    float s = 0.f;
    #pragma unroll
    for (int j = 0; j < 8; ++j) {
        const float4 a = *(const float4*)(wr + j * 256 + lane * 4);
        const float4 b = *(const float4*)(h1 + j * 256 + lane * 4);
        s += a.x * b.x + a.y * b.y + a.z * b.z + a.w * b.w;
    }
    #pragma unroll
    for (int off = 32; off > 0; off >>= 1) s += __shfl_down(s, off);
    if (lane == 0) {
        const float val = s + b1[row];
        h2[row] = val / (1.0f + expf(-val));   // silu
    }
}

// ---------------------------------------------------------------------------
// K_alpha: alpha = sigmoid(h2 . W2 + b2). One block x 256.
// ---------------------------------------------------------------------------
__global__ __launch_bounds__(256) void k_alpha(
    const float* __restrict__ h2, const float* __restrict__ W2,
    const float* __restrict__ b2,
    float* __restrict__ alpha_ws, float* __restrict__ out_alpha)
{
    __shared__ float red[256];
    const int t = threadIdx.x;
    float s = 0.f;
    for (int i = t; i < DM; i += 256) s += h2[i] * W2[i];
    red[t] = s; __syncthreads();
    for (int off = 128; off > 0; off >>= 1) {
        if (t < off) red[t] += red[t + off];
        __syncthreads();
    }
    if (t == 0) {
        const float logit = red[0] + b2[0];
        const float a = 1.0f / (1.0f + expf(-logit));
        alpha_ws[0] = a;
        out_alpha[0] = a;
    }
}

// ---------------------------------------------------------------------------
// K_update: gradB/gradC -> S_B_new/S_C_new -> B_new/C_new. 128 blocks x 256.
//   WC  = W@C   ~= SCALE*B(CtC) + D o C
//   WTB = W^T@B ~= SCALE*C(BtB) + D o B
// ---------------------------------------------------------------------------
__global__ __launch_bounds__(256) void k_update(
    const float* __restrict__ B, const float* __restrict__ C,
    const float* __restrict__ Dd,
    const float* __restrict__ S_B, const float* __restrict__ S_C,
    const float* __restrict__ G1, const float* __restrict__ G2,
    const float* __restrict__ CtC, const float* __restrict__ BtB,
    const float* __restrict__ alpha_ws,
    float* __restrict__ outB, float* __restrict__ outC,
    float* __restrict__ outSB, float* __restrict__ outSC)
{
    const int idx = blockIdx.x * 256 + threadIdx.x;   // [0, 32768)
    const int d = idx >> 4, r = idx & 15;
    const float alpha = alpha_ws[0];

    float Brow[16], Crow[16];
    #pragma unroll
    for (int q = 0; q < 4; ++q) {
        const float4 b4 = *(const float4*)(B + (size_t)d * RK + q * 4);
        const float4 c4 = *(const float4*)(C + (size_t)d * RK + q * 4);
        Brow[q*4+0] = b4.x; Brow[q*4+1] = b4.y; Brow[q*4+2] = b4.z; Brow[q*4+3] = b4.w;
        Crow[q*4+0] = c4.x; Crow[q*4+1] = c4.y; Crow[q*4+2] = c4.z; Crow[q*4+3] = c4.w;
    }
    float bc = 0.f, cb = 0.f;
    #pragma unroll
    for (int a = 0; a < 16; ++a) {
        bc += Brow[a] * CtC[a * RK + r];
        cb += Crow[a] * BtB[a * RK + r];
    }
    const float Ddv = Dd[d];
    const float invN = 1.0f / (float)NROWS;   // fp32(16384 + 1e-8) == 16384
    const float gradB = -G1[idx] * invN + L2c * (SCALEc * bc + Ddv * Crow[r]);
    const float gradC = -G2[idx] * invN + L2c * (SCALEc * cb + Ddv * Brow[r]);
    const float sB = MOMc * S_B[idx] - LRc * gradB;
    const float sC = MOMc * S_C[idx] - LRc * gradC;
    outSB[idx] = sB;
    outSC[idx] = sC;
    outB[idx] = (1.0f - alpha) * B[idx] + sB;
    outC[idx] = (1.0f - alpha) * C[idx] + sC;
}

// ---------------------------------------------------------------------------
extern "C" void kernel_launch(void* const* d_in, const int* in_sizes, int n_in,
                              void* d_out, int out_size, void* d_ws, size_t ws_size,
                              hipStream_t stream)
{
    const float* k   = (const float*)d_in[0];
    const float* v   = (const float*)d_in[1];
    const float* B   = (const float*)d_in[2];
    const float* C   = (const float*)d_in[3];
    const float* Dd  = (const float*)d_in[4];
    const float* S_B = (const float*)d_in[5];
    const float* S_C = (const float*)d_in[6];
    const float* gam = (const float*)d_in[7];
    const float* bet = (const float*)d_in[8];
    const float* W1  = (const float*)d_in[9];
    const float* b1  = (const float*)d_in[10];
    const float* W2  = (const float*)d_in[11];
    const float* b2  = (const float*)d_in[12];

    float* out      = (float*)d_out;
    float* ro       = out;                                  // [N, D]
    float* outB     = out + (size_t)NROWS * DM;             // [D, R]
    float* outC     = outB + (size_t)DM * RK;
    float* outSB    = outC + (size_t)DM * RK;
    float* outSC    = outSB + (size_t)DM * RK;
    float* outAlpha = outSC + (size_t)DM * RK;              // scalar

    float* ws     = (float*)d_ws;
    float* kC     = ws;                                     // N*R
    float* errB   = kC + (size_t)NROWS * RK;                // N*R
    float* colsum = errB + (size_t)NROWS * RK;              // D
    float* G1     = colsum + DM;                            // D*R
    float* G2     = G1 + (size_t)DM * RK;                   // D*R
    float* CtC    = G2 + (size_t)DM * RK;                   // 256
    float* BtB    = CtC + 256;                              // 256
    float* h1     = BtB + 256;                              // D
    float* h2     = h1 + DM;                                // D
    float* alphaW = h2 + DM;                                // 1

    // zero the accumulators (colsum, G1, G2, CtC, BtB)
    hipMemsetAsync(colsum, 0, (size_t)(DM + 2 * DM * RK + 512) * sizeof(float), stream);

    hipLaunchKernelGGL(k_main, dim3(256), dim3(512), 0, stream,
                       k, v, B, C, Dd, ro, kC, errB, colsum);
    hipLaunchKernelGGL(k_grad, dim3(512), dim3(256), 0, stream,
                       k, v, ro, kC, errB, G1, G2);
    hipLaunchKernelGGL(k_ctc, dim3(16), dim3(256), 0, stream, B, C, BtB, CtC);
    hipLaunchKernelGGL(k_ln, dim3(1), dim3(256), 0, stream, colsum, gam, bet, h1);
    hipLaunchKernelGGL(k_gemv, dim3(512), dim3(256), 0, stream, h1, W1, b1, h2);
    hipLaunchKernelGGL(k_alpha, dim3(1), dim3(256), 0, stream, h2, W2, b2, alphaW, outAlpha);
    hipLaunchKernelGGL(k_update, dim3(128), dim3(256), 0, stream,
                       B, C, Dd, S_B, S_C, G1, G2, CtC, BtB, alphaW,
                       outB, outC, outSB, outSC);
}